// Round 9
// baseline (236.322 us; speedup 1.0000x reference)
//
#include <hip/hip_runtime.h>

// SelfAttentiveLBLBiLM on MI355X — round 16.
// r15 post-mortem: total 232.6 (-3, sliding-window proj worked). The
// clock-depressed profile pass (QKV 44->53 on identical code) surfaced
// k_gemm256 EPI=2 at ~44us nominal with FETCH 42.5MB vs 19 ideal: the gate
// epilogue re-reads A as 64 scalar 2B global loads/thread (8.4M/dispatch,
// half-coalesced, unhidden latency at kernel tail) — the hw-specific tax
// that makes hw 1.5x less efficient than QKV per-FLOP in the same pass.
// Fix: after the K loop (LDS dead, staging drained), cooperatively stage
// the 64KB gate slice into smem via global_load_lds (16B/lane coalesced),
// bank-swizzled by pre-swizzled SOURCE (byte ^= (row&12)<<3, involution,
// reader applies same XOR -> 32 banks, conflict-free), then ds_read_u16.
// Dispatches: prep_w, prep_x, qkv(128^2+XCD swz), attn(4-row),
// proj+rel(128^2 sliding), hw 256^2 8-phase x2 (gate via LDS).

#define B_ 8
#define S_ 1024
#define D_ 512
#define H_ 8
#define DK_ 64
#define WIDTH_ 8
#define S2_ 1040
#define NHW_ 2

typedef short bf16x8 __attribute__((ext_vector_type(8)));
typedef float f32x4 __attribute__((ext_vector_type(4)));

__device__ __forceinline__ float us2f(unsigned short u) {
  union { unsigned int i; float f; } c; c.i = ((unsigned int)u) << 16; return c.f;
}
__device__ __forceinline__ unsigned short f2us(float f) {
  union { float f; unsigned int i; } c; c.f = f;
  unsigned int x = c.i;
  return (unsigned short)((x + 0x7fffu + ((x >> 16) & 1u)) >> 16);
}
__device__ __forceinline__ unsigned int pack2(float a, float b) {
  return (unsigned int)f2us(a) | ((unsigned int)f2us(b) << 16);
}
__device__ __forceinline__ void async16(const void* g, void* l) {
  __builtin_amdgcn_global_load_lds(
      (const __attribute__((address_space(1))) void*)g,
      (__attribute__((address_space(3))) void*)l, 16, 0, 0);
}
__device__ __forceinline__ void unpack8(uint4 u, float* f) {
  unsigned int w[4] = {u.x, u.y, u.z, u.w};
  #pragma unroll
  for (int c = 0; c < 4; ++c) {
    union { unsigned int i; float g; } lo, hi;
    lo.i = w[c] << 16;
    hi.i = w[c] & 0xffff0000u;
    f[2 * c] = lo.g;
    f[2 * c + 1] = hi.g;
  }
}

// ---------------------------------------------------------------------------
// Prep (weights): [0,2048) attn W transpose; [2048,4096) hw W transpose.
__global__ __launch_bounds__(256) void k_prep_w(
    const float* __restrict__ lW, const float* __restrict__ rW,
    const float* __restrict__ lhwW, const float* __restrict__ rhwW,
    unsigned short* __restrict__ WTall, unsigned short* __restrict__ WTp,
    unsigned short* __restrict__ hWT)
{
  __shared__ float tile[32][33];
  const size_t DD = (size_t)D_ * D_;
  int bx = blockIdx.x;
  int tx = threadIdx.x & 31, ty = threadIdx.x >> 5;

  if (bx < 2048) {                     // ---- attn transpose
    int sl = bx >> 8, rem = bx & 255;
    int side = sl >> 2, slice = sl & 3;
    int c0 = (rem & 15) * 32, r0 = (rem >> 4) * 32;
    const float* src = (side ? rW : lW) + (size_t)slice * DD;
    unsigned short* dst = (slice < 3) ? WTall + (size_t)(side * 3 + slice) * DD
                                      : WTp + (size_t)side * DD;
    #pragma unroll
    for (int i = 0; i < 4; ++i)
      tile[ty + i * 8][tx] = src[(size_t)(r0 + ty + i * 8) * D_ + c0 + tx];
    __syncthreads();
    #pragma unroll
    for (int i = 0; i < 4; ++i)
      dst[(size_t)(c0 + ty + i * 8) * D_ + r0 + tx] = f2us(tile[tx][ty + i * 8]);
    return;
  }
  // ---- hw transpose + interleave (256-tile pairing)
  int idx = bx - 2048;
  int sl = idx >> 9, rem = idx & 511;    // sl: side*2+layer
  int c0 = (rem & 31) * 32, r0 = (rem >> 5) * 32;
  const float* src = ((sl >> 1) ? rhwW : lhwW) + (size_t)(sl & 1) * 512 * 1024;
  unsigned short* dst = hWT + (size_t)sl * 1024 * 512;
  #pragma unroll
  for (int i = 0; i < 4; ++i)
    tile[ty + i * 8][tx] = src[(size_t)(r0 + ty + i * 8) * 1024 + c0 + tx];
  __syncthreads();
  #pragma unroll
  for (int i = 0; i < 4; ++i) {
    int c = c0 + ty + i * 8;
    int cm = c & 511;
    int j = cm >> 4;                       // 16-col block of x, 0..31
    int jl = j & 7;
    int Bq = ((jl >> 2) << 3) + (jl & 3) + ((c >= 512) ? 4 : 0);
    int q = (j >> 3) * 256 + Bq * 16 + (cm & 15);
    dst[(size_t)q * 512 + r0 + tx] = f2us(tile[tx][ty + i * 8]);
  }
}

// ---------------------------------------------------------------------------
// Prep (activations): build new_in + qkv bias tail.
__global__ __launch_bounds__(256) void k_prep_x(
    const float* __restrict__ x,
    const float* __restrict__ lpad, const float* __restrict__ rpad,
    const float* __restrict__ lb, const float* __restrict__ rb,
    unsigned short* __restrict__ nin, float* __restrict__ qkvbias)
{
  int gid = blockIdx.x * 256 + threadIdx.x;
  const int NTH = B_ * S2_ * 64;       // 532,480
  if (gid >= NTH) {
    int t = gid - NTH;
    if (t < 1536) qkvbias[t] = lb[t];
    else if (t < 3072) qkvbias[t] = rb[t - 1536];
    return;
  }
  int c8 = (gid & 63) << 3;
  int row = gid >> 6;
  int b = row / S2_;
  int t = row - b * S2_;
  const float* src;
  if (t < WIDTH_)            src = lpad + (size_t)t * D_ + c8;
  else if (t >= S_ + WIDTH_) src = rpad + (size_t)(t - S_ - WIDTH_) * D_ + c8;
  else                       src = x + ((size_t)b * S_ + (t - WIDTH_)) * D_ + c8;
  float4 a = *reinterpret_cast<const float4*>(src);
  float4 c = *reinterpret_cast<const float4*>(src + 4);
  uint4 o;
  o.x = pack2(a.x, a.y); o.y = pack2(a.z, a.w);
  o.z = pack2(c.x, c.y); o.w = pack2(c.z, c.w);
  *reinterpret_cast<uint4*>(nin + (size_t)row * D_ + c8) = o;
}

// ---------------------------------------------------------------------------
// MFMA GEMM (QKV): C(M,N) = A(M,K) @ BT(N,K)^T + bias(N).
// BK=64, XOR-swizzled LDS, tile 128x128, 4 waves, XCD-swizzled grid.
__global__ __launch_bounds__(256) void k_gemm_mfma(
    const unsigned short* __restrict__ A,
    const unsigned short* __restrict__ BT,
    const float* __restrict__ bias,
    unsigned short* __restrict__ C,
    int M, int N, int K)
{
  __shared__ unsigned short As[128 * 64];
  __shared__ unsigned short Bs[128 * 64];

  const int tid = threadIdx.x;
  const int w = tid >> 6;
  const int l = tid & 63;

  // bijective XCD swizzle (nwg % 8 == 0)
  const int gx = gridDim.x;
  const int nwg = gx * gridDim.y;
  const int flat = blockIdx.y * gx + blockIdx.x;
  const int cpx = nwg >> 3;
  const int nf = (flat & 7) * cpx + (flat >> 3);
  const int bm = (nf / gx) * 128;
  const int bn = (nf % gx) * 128;

  const int wrow = (w >> 1) * 64;
  const int wcol = (w & 1) * 64;

  const int lr = l >> 3;
  const int sk = (((l & 7) ^ lr) & 7) * 8;
  const unsigned short* Ap = A + (size_t)(bm + w * 8 + lr) * K + sk;
  const unsigned short* Bp = BT + (size_t)(bn + w * 8 + lr) * K + sk;
  unsigned short* lA = &As[w * 512];
  unsigned short* lB = &Bs[w * 512];
  const size_t K32 = (size_t)32 * K;

  const int fl = l & 15;
  const int fq = l >> 4;
  const int fx = fl & 7;

  f32x4 acc[4][4];
  #pragma unroll
  for (int mi = 0; mi < 4; ++mi)
    #pragma unroll
    for (int ni = 0; ni < 4; ++ni) acc[mi][ni] = (f32x4){0.f, 0.f, 0.f, 0.f};

  for (int k0 = 0; k0 < K; k0 += 64) {
    #pragma unroll
    for (int r = 0; r < 4; ++r) {
      async16(Ap + k0 + r * K32, lA + r * 2048);
      async16(Bp + k0 + r * K32, lB + r * 2048);
    }
    __syncthreads();
    #pragma unroll
    for (int s = 0; s < 2; ++s) {
      bf16x8 af[4], bfr[4];
      #pragma unroll
      for (int mi = 0; mi < 4; ++mi)
        af[mi] = *reinterpret_cast<const bf16x8*>(
            &As[(wrow + mi * 16 + fl) * 64 + (((s * 4 + fq) ^ fx) * 8)]);
      #pragma unroll
      for (int ni = 0; ni < 4; ++ni)
        bfr[ni] = *reinterpret_cast<const bf16x8*>(
            &Bs[(wcol + ni * 16 + fl) * 64 + (((s * 4 + fq) ^ fx) * 8)]);
      #pragma unroll
      for (int mi = 0; mi < 4; ++mi)
        #pragma unroll
        for (int ni = 0; ni < 4; ++ni)
          acc[mi][ni] = __builtin_amdgcn_mfma_f32_16x16x32_bf16(
              af[mi], bfr[ni], acc[mi][ni], 0, 0, 0);
    }
    __syncthreads();
  }

  float bv[4];
  #pragma unroll
  for (int ni = 0; ni < 4; ++ni) bv[ni] = bias[bn + wcol + ni * 16 + fl];

  const int rbase = (l >> 4) * 4;
  #pragma unroll
  for (int mi = 0; mi < 4; ++mi) {
    #pragma unroll
    for (int r = 0; r < 4; ++r) {
      int row = bm + wrow + mi * 16 + rbase + r;
      unsigned short* Cp = C + (size_t)row * N + bn + wcol + fl;
      #pragma unroll
      for (int ni = 0; ni < 4; ++ni)
        Cp[ni * 16] = f2us(acc[mi][ni][r] + bv[ni]);
    }
  }
}

// ---------------------------------------------------------------------------
// 256x256 8-phase GEMM, K=512 (hw layers only: grid exactly 256 blocks).
//  EPI=1: highway gate -> bf16 (z*MS + row*512 + x)
//  EPI=2: highway gate -> f32  (row*1024 + z*512 + x)
// r16: gate xv via LDS — after K loop, stage the 256x128 A gate slice into
// the dead smem (global_load_lds, source pre-swizzled byte^=(row&12)<<3),
// read back conflict-free with ds_read_u16 (reader applies same XOR).
template <int EPI>
__global__ __launch_bounds__(512, 2) void k_gemm256(
    const unsigned short* __restrict__ Abase, size_t aStrZ,
    const unsigned short* __restrict__ BTbase, size_t bStrZ,
    const float* __restrict__ bias0, const float* __restrict__ bias1,
    unsigned short* __restrict__ Cbf, float* __restrict__ Cfp,
    int M, int N)
{
  __shared__ __align__(16) unsigned short smem[65536];   // 128 KiB
  const int tid = threadIdx.x;
  const int w = tid >> 6, l = tid & 63;
  const int wm = w >> 2, wn = w & 3;
  const int fl = l & 15, fq = l >> 4;
  const int z = blockIdx.z;
  const unsigned short* A = Abase + (size_t)z * aStrZ;
  const unsigned short* BT = BTbase + (size_t)z * bStrZ;
  const int bm = blockIdx.y * 256, bn = blockIdx.x * 256;

  const int xorb = (fl & 7) << 4;
  const int cs0 = ((fq * 16) ^ xorb) >> 1;        // k-slice 0
  const int cs1 = ((64 + fq * 16) ^ xorb) >> 1;   // k-slice 1

  const int rr = l >> 3;
  const int ce = (((l & 7) * 16) ^ (rr << 4)) >> 1;   // shorts
  const unsigned short* gA[2][2];
  const unsigned short* gB[2][2];
  #pragma unroll
  for (int i = 0; i < 2; ++i)
    #pragma unroll
    for (int h = 0; h < 2; ++h) {
      int ra = bm + h * 128 + (2 * w + i) * 8 + rr;
      if (ra > M - 1) ra = M - 1;
      gA[i][h] = A + (size_t)ra * 512 + ce;
      int rb = bn + h * 128 + (2 * w + i) * 8 + rr;
      gB[i][h] = BT + (size_t)rb * 512 + ce;
    }

  f32x4 acc[8][4];
  #pragma unroll
  for (int mi = 0; mi < 8; ++mi)
    #pragma unroll
    for (int ni = 0; ni < 4; ++ni) acc[mi][ni] = (f32x4){0.f, 0.f, 0.f, 0.f};

  bf16x8 ar[4][2], br[2][2];

#define BAR() __builtin_amdgcn_s_barrier()
#define STGA(buf, h, kt) do { \
    async16(gA[0][h] + (kt) * 64, &smem[((buf) * 2 + (h)) * 8192 + (2 * w) * 512]); \
    async16(gA[1][h] + (kt) * 64, &smem[((buf) * 2 + (h)) * 8192 + (2 * w + 1) * 512]); } while (0)
#define STGB(buf, h, kt) do { \
    async16(gB[0][h] + (kt) * 64, &smem[32768 + ((buf) * 2 + (h)) * 8192 + (2 * w) * 512]); \
    async16(gB[1][h] + (kt) * 64, &smem[32768 + ((buf) * 2 + (h)) * 8192 + (2 * w + 1) * 512]); } while (0)
#define LDA(buf, h) do { const unsigned short* p_ = &smem[((buf) * 2 + (h)) * 8192]; \
    _Pragma("unroll") for (int m4 = 0; m4 < 4; ++m4) { \
      int ro_ = ((2 * m4 + wm) * 16 + fl) * 64; \
      ar[m4][0] = *reinterpret_cast<const bf16x8*>(p_ + ro_ + cs0); \
      ar[m4][1] = *reinterpret_cast<const bf16x8*>(p_ + ro_ + cs1); } } while (0)
#define LDB(buf, h) do { const unsigned short* p_ = &smem[32768 + ((buf) * 2 + (h)) * 8192]; \
    _Pragma("unroll") for (int n2 = 0; n2 < 2; ++n2) { \
      int ro_ = ((4 * n2 + wn) * 16 + fl) * 64; \
      br[n2][0] = *reinterpret_cast<const bf16x8*>(p_ + ro_ + cs0); \
      br[n2][1] = *reinterpret_cast<const bf16x8*>(p_ + ro_ + cs1); } } while (0)
#define QUAD(miH, niH) do { __builtin_amdgcn_s_setprio(1); \
    _Pragma("unroll") for (int m4 = 0; m4 < 4; ++m4) \
      _Pragma("unroll") for (int n2 = 0; n2 < 2; ++n2) \
        _Pragma("unroll") for (int s_ = 0; s_ < 2; ++s_) \
          acc[(miH) * 4 + m4][(niH) * 2 + n2] = __builtin_amdgcn_mfma_f32_16x16x32_bf16( \
              ar[m4][s_], br[n2][s_], acc[(miH) * 4 + m4][(niH) * 2 + n2], 0, 0, 0); \
    __builtin_amdgcn_s_setprio(0); } while (0)

  // prologue: T0 {A0,B0,B1,A1} -> buf0, T1 {A0,B1,A1} -> buf1 (B0 at I1).
  STGA(0, 0, 0); STGB(0, 0, 0); STGB(0, 1, 0); STGA(0, 1, 0);
  STGA(1, 0, 1); STGB(1, 1, 1); STGA(1, 1, 1);
  asm volatile("s_waitcnt vmcnt(6)" ::: "memory");   // T0 fully landed
  BAR();

  #pragma unroll 1
  for (int it = 0; it < 4; ++it) {
    const int t1 = 2 * it + 1, t2 = 2 * it + 2, t3 = 2 * it + 3;
    LDA(0, 0); LDB(0, 0);
    STGB(1, 0, t1);
    BAR(); QUAD(0, 0); BAR();
    LDB(0, 1);
    if (t2 < 8) STGA(0, 0, t2);
    BAR(); QUAD(0, 1); BAR();
    LDA(0, 1);
    if (t2 < 8) STGB(0, 1, t2);
    BAR(); QUAD(1, 1); BAR();
    LDB(0, 0);
    if (t2 < 8) STGA(0, 1, t2);
    BAR(); QUAD(1, 0);
    if (it < 3) asm volatile("s_waitcnt vmcnt(6)" ::: "memory");
    else        asm volatile("s_waitcnt vmcnt(0)" ::: "memory");
    BAR();
    LDA(1, 0); LDB(1, 0);
    if (t2 < 8) STGB(0, 0, t2);
    BAR(); QUAD(0, 0); BAR();
    LDB(1, 1);
    if (t3 < 8) STGA(1, 0, t3);
    BAR(); QUAD(0, 1); BAR();
    LDA(1, 1);
    if (t3 < 8) STGB(1, 1, t3);
    BAR(); QUAD(1, 1); BAR();
    LDB(1, 0);
    if (t3 < 8) STGA(1, 1, t3);
    BAR(); QUAD(1, 0);
    asm volatile("s_waitcnt vmcnt(6)" ::: "memory");
    BAR();
  }
#undef BAR
#undef STGA
#undef STGB
#undef LDA
#undef LDB
#undef QUAD

  // ---- gate-slice staging: A[bm..bm+256) x [bx*128..bx*128+128) -> smem
  // (64 KB, dead after final barrier; it=3's ph4 vmcnt(0) drained staging).
  // LDS(row, db) holds global col byte db ^ ((row&12)<<3)  [involution].
  {
    const unsigned short* gsrc = A + (size_t)bm * 512 + blockIdx.x * 128;
    #pragma unroll
    for (int i = 0; i < 8; ++i) {
      int row = (w * 8 + i) * 4 + (l >> 4);            // 0..255
      int sb = ((l & 15) * 16) ^ ((row & 12) << 3);    // src byte in row
      async16(gsrc + (size_t)row * 512 + (sb >> 1),
              &smem[(w * 8 + i) * 512 + l * 8]);
    }
  }
  asm volatile("s_waitcnt vmcnt(0)" ::: "memory");
  __builtin_amdgcn_s_barrier();

  // ---- epilogue (hw gate; xv from LDS, conflict-free via matching XOR)
  {
    const float* bias = z ? bias1 : bias0;
    const size_t MS = (size_t)B_ * S_ * D_;
    float bnl[2], bg[2]; int xs[2];
    #pragma unroll
    for (int np = 0; np < 2; ++np) {
      xs[np] = (blockIdx.x * 8 + np * 4 + wn) * 16 + fl;
      bnl[np] = bias[xs[np]];
      bg[np]  = bias[512 + xs[np]];
    }
    #pragma unroll
    for (int mi = 0; mi < 8; ++mi) {
      #pragma unroll
      for (int r = 0; r < 4; ++r) {
        int lrow = (2 * mi + wm) * 16 + fq * 4 + r;    // 0..255
        int gr = bm + lrow;
        #pragma unroll
        for (int np = 0; np < 2; ++np) {
          int rb = ((np * 64 + wn * 16 + fl) * 2) ^ ((lrow & 12) << 3);
          float xv = us2f(smem[lrow * 128 + (rb >> 1)]);
          float nl = fmaxf(acc[mi][2 * np][r] + bnl[np], 0.f);
          float g  = 1.f / (1.f + __expf(-(acc[mi][2 * np + 1][r] + bg[np])));
          float res = g * xv + (1.f - g) * nl;
          if (EPI == 2) Cfp[(size_t)gr * 1024 + (size_t)z * 512 + xs[np]] = res;
          else Cbf[(size_t)z * MS + (size_t)gr * 512 + xs[np]] = f2us(res);
        }
      }
    }
  }
}

// ---------------------------------------------------------------------------
// Proj GEMM + fused rel-add (128^2 structure, sliding-window rel-add).
__global__ __launch_bounds__(256) void k_gemm_proj(
    const unsigned short* __restrict__ ctx,
    const unsigned short* __restrict__ WTp,    // (2,512,512)
    const unsigned short* __restrict__ nin,    // (B,S2,512)
    const float* __restrict__ lb3, const float* __restrict__ rb3,
    const float* __restrict__ wrel0, const float* __restrict__ wrel1,
    unsigned short* __restrict__ hwx)          // (2,8192,512)
{
  __shared__ unsigned short smem[128 * 136];   // 34.8 KB; staging uses 32 KB
  unsigned short* As = smem;
  unsigned short* Bs = smem + 8192;
  const int K = 512;
  const size_t MS = (size_t)B_ * S_ * D_;

  const int z = blockIdx.z;
  const unsigned short* A = ctx + (size_t)z * MS;
  const unsigned short* BT = WTp + (size_t)z * 512 * 512;
  const float* bias = z ? rb3 : lb3;
  const float* wrel = z ? wrel1 : wrel0;
  const int off = z * WIDTH_;

  const int tid = threadIdx.x;
  const int w = tid >> 6;
  const int l = tid & 63;
  const int bm = blockIdx.y * 128;
  const int bn = blockIdx.x * 128;
  const int wrow = (w >> 1) * 64;
  const int wcol = (w & 1) * 64;

  const int lr = l >> 3;
  const int sk = (((l & 7) ^ lr) & 7) * 8;
  const unsigned short* Ap = A + (size_t)(bm + w * 8 + lr) * K + sk;
  const unsigned short* Bp = BT + (size_t)(bn + w * 8 + lr) * K + sk;
  unsigned short* lA = &As[w * 512];
  unsigned short* lB = &Bs[w * 512];
  const size_t K32 = (size_t)32 * K;

  const int fl = l & 15;
  const int fq = l >> 4;
  const int fx = fl & 7;

  f32x4 acc[4][4];
  #pragma unroll
  for (int mi = 0; mi < 4; ++mi)
    #pragma unroll
    for (int ni = 0; ni < 4; ++ni) acc[mi][ni] = (f32x4){0.f, 0.f, 0.f, 0.f};

  for (int k0 = 0; k0 < K; k0 += 64) {
    #pragma unroll
    for (int r = 0; r < 4; ++r) {
      async16(Ap + k0 + r * K32, lA + r * 2048);
      async16(Bp + k0 + r * K32, lB + r * 2048);
    }
    __syncthreads();
    #pragma unroll
    for (int s = 0; s < 2; ++s) {
      bf16x8 af[4], bfr[4];
      #pragma unroll
      for (int mi = 0; mi < 4; ++mi)
        af[mi] = *reinterpret_cast<const bf16x8*>(
            &As[(wrow + mi * 16 + fl) * 64 + (((s * 4 + fq) ^ fx) * 8)]);
      #pragma unroll
      for (int ni = 0; ni < 4; ++ni)
        bfr[ni] = *reinterpret_cast<const bf16x8*>(
            &Bs[(wcol + ni * 16 + fl) * 64 + (((s * 4 + fq) ^ fx) * 8)]);
      #pragma unroll
      for (int mi = 0; mi < 4; ++mi)
        #pragma unroll
        for (int ni = 0; ni < 4; ++ni)
          acc[mi][ni] = __builtin_amdgcn_mfma_f32_16x16x32_bf16(
              af[mi], bfr[ni], acc[mi][ni], 0, 0, 0);
    }
    __syncthreads();
  }

  // stage bias-added tile into LDS (bf16, ld 136)
  float bv[4];
  #pragma unroll
  for (int ni = 0; ni < 4; ++ni) bv[ni] = bias[bn + wcol + ni * 16 + fl];
  const int rbase = (l >> 4) * 4;
  #pragma unroll
  for (int mi = 0; mi < 4; ++mi)
    #pragma unroll
    for (int r = 0; r < 4; ++r)
      #pragma unroll
      for (int ni = 0; ni < 4; ++ni)
        smem[(wrow + mi * 16 + rbase + r) * 136 + wcol + ni * 16 + fl] =
            f2us(acc[mi][ni][r] + bv[ni]);
  __syncthreads();

  // sliding-window rel-add: thread = (8-consecutive-row group, 8-col chunk).
  const float wj[9] = {wrel[0], wrel[1], wrel[2], wrel[3], wrel[4],
                       wrel[5], wrel[6], wrel[7], wrel[8]};
  const int g8 = (tid >> 4) * 8;
  const int tcol = (tid & 15) * 8;
  {
    int gr0 = bm + g8;
    int b0 = gr0 >> 10, s0 = gr0 & (S_ - 1);
    const unsigned short* np =
        nin + ((size_t)b0 * S2_ + off + s0) * D_ + bn + tcol;
    unsigned short* op = hwx + (size_t)z * MS + (size_t)gr0 * D_ + bn + tcol;
    #pragma unroll
    for (int h = 0; h < 2; ++h) {          // rows h*4 .. h*4+3 of the group
      float a4[4][8];
      #pragma unroll
      for (int i = 0; i < 4; ++i)
        unpack8(*reinterpret_cast<const uint4*>(
            &smem[(g8 + h * 4 + i) * 136 + tcol]), a4[i]);
      #pragma unroll
      for (int t = 0; t < 12; ++t) {       // absolute taps h*4 .. h*4+11
        float nf[8];
        unpack8(*reinterpret_cast<const uint4*>(
            np + (size_t)(h * 4 + t) * D_), nf);
        #pragma unroll
        for (int i = 0; i < 4; ++i) {
          if (t < i || t > i + 8) continue;
          float wv = wj[t - i];
          #pragma unroll
          for (int e = 0; e < 8; ++e) a4[i][e] += wv * nf[e];
        }
      }
      #pragma unroll
      for (int i = 0; i < 4; ++i) {
        uint4 o;
        o.x = pack2(a4[i][0], a4[i][1]); o.y = pack2(a4[i][2], a4[i][3]);
        o.z = pack2(a4[i][4], a4[i][5]); o.w = pack2(a4[i][6], a4[i][7]);
        *reinterpret_cast<uint4*>(op + (size_t)(h * 4 + i) * D_) = o;
      }
    }
  }
}

// ---------------------------------------------------------------------------
// Windowed attention, 4 consecutive rows per wave sharing a 13-row K/V
// window (r11-proven).
__global__ __launch_bounds__(256) void k_attn_window(
    const unsigned short* __restrict__ qkv,
    unsigned short* __restrict__ ctx)
{
  int wid = (blockIdx.x * 256 + threadIdx.x) >> 6;   // dir*2048 + b*256 + sg
  int lane = threadIdx.x & 63;
  int sg = wid & 255;
  int b = (wid >> 8) & 7;
  int dir = wid >> 11;
  int s0 = sg << 2;
  int i0 = s0 + WIDTH_;

  const size_t base = (size_t)b * S2_ * 3072 + dir * 1536;
  const int c0 = lane * 8;

  float qf[4][8];
  #pragma unroll
  for (int r = 0; r < 4; ++r)
    unpack8(*reinterpret_cast<const uint4*>(
        qkv + base + (size_t)(i0 + r) * 3072 + c0), qf[r]);

  float sc[4][10];
  float mx[4] = {-1e30f, -1e30f, -1e30f, -1e30f};
  #pragma unroll
  for (int t = 0; t < 13; ++t) {
    int j = (dir == 0) ? (i0 - 9 + t) : (i0 + t);
    bool ok = (j >= 0 && j < S2_);           // wave-uniform
    float kf[8];
    if (ok)
      unpack8(*reinterpret_cast<const uint4*>(
          qkv + base + (size_t)j * 3072 + 512 + c0), kf);
    #pragma unroll
    for (int r = 0; r < 4; ++r) {
      if (t < r || t > r + 9) continue;      // compile-time prune
      float sv = -1e30f;
      if (ok) {
        float p = qf[r][0] * kf[0];
        #pragma unroll
        for (int e = 1; e < 8; ++e) p += qf[r][e] * kf[e];
        p += __shfl_xor(p, 1);
        p += __shfl_xor(p, 2);
        p += __shfl_xor(p, 4);
        sv = p * 0.125f;
      }
      sc[r][t - r] = sv;
      mx[r] = fmaxf(mx[r], sv);
    }
  }

  float inv[4];
  #pragma unroll
  for (int r = 0; r < 4; ++r) {
    float den = 0.f;
    #pragma unroll
    for (int u = 0; u < 10; ++u) {
      sc[r][u] = (sc[r][u] > -1e29f) ? __expf(sc[r][u] - mx[r]) : 0.f;
      den += sc[r][u];
    }
    inv[r] = 1.f / den;
  }

  float acc[4][8];
  #pragma unroll
  for (int r = 0; r < 4; ++r)
    #pragma unroll
    for (int e = 0; e < 8; ++e) acc[r][e] = 0.f;

  #pragma unroll
  for (int t = 0; t < 13; ++t) {
    int j = (dir == 0) ? (i0 - 9 + t) : (i0 + t);
    bool ok = (j >= 0 && j < S2_);
    float vf[8];
    if (ok)
      unpack8(*reinterpret_cast<const uint4*>(
          qkv + base + (size_t)j * 3072 + 1024 + c0), vf);
    #pragma unroll
    for (int r = 0; r < 4; ++r) {
      if (t < r || t > r + 9) continue;
      if (ok) {
        float p = sc[r][t - r];
        #pragma unroll
        for (int e = 0; e < 8; ++e) acc[r][e] += p * vf[e];
      }
    }
  }

  #pragma unroll
  for (int r = 0; r < 4; ++r) {
    uint4 o;
    o.x = pack2(acc[r][0] * inv[r], acc[r][1] * inv[r]);
    o.y = pack2(acc[r][2] * inv[r], acc[r][3] * inv[r]);
    o.z = pack2(acc[r][4] * inv[r], acc[r][5] * inv[r]);
    o.w = pack2(acc[r][6] * inv[r], acc[r][7] * inv[r]);
    *reinterpret_cast<uint4*>(
        ctx + (((size_t)dir * B_ + b) * S_ + s0 + r) * D_ + c0) = o;
  }
}

// ---------------------------------------------------------------------------
extern "C" void kernel_launch(void* const* d_in, const int* in_sizes, int n_in,
                              void* d_out, int out_size, void* d_ws, size_t ws_size,
                              hipStream_t stream) {
  const float* x    = (const float*)d_in[0];
  const float* lW   = (const float*)d_in[1];
  const float* lb   = (const float*)d_in[2];
  const float* rW   = (const float*)d_in[3];
  const float* rb   = (const float*)d_in[4];
  const float* lpad = (const float*)d_in[5];
  const float* rpad = (const float*)d_in[6];
  const float* lw   = (const float*)d_in[7];
  const float* rw   = (const float*)d_in[8];
  const float* lhwW = (const float*)d_in[9];
  const float* lhwb = (const float*)d_in[10];
  const float* rhwW = (const float*)d_in[11];
  const float* rhwb = (const float*)d_in[12];
  float* out = (float*)d_out;
  unsigned short* ws = (unsigned short*)d_ws;

  const size_t NIN  = (size_t)B_ * S2_ * D_;       // 4,259,840
  const size_t NQKV = (size_t)B_ * S2_ * 3072;     // 25,559,040
  const size_t MS   = (size_t)B_ * S_ * D_;        // 4,194,304
  const size_t DD   = (size_t)D_ * D_;             // 262,144
  const size_t LHW  = (size_t)1024 * 512;          // 524,288

  unsigned short* nin   = ws;
  unsigned short* qkv   = nin + NIN;
  unsigned short* ctx   = qkv + NQKV;              // (2,B,S,D)
  unsigned short* hwx   = ctx + 2 * MS;            // (2,B,S,D)
  unsigned short* hwy   = hwx + 2 * MS;            // (2,B,S,D)
  unsigned short* WTall = hwy + 2 * MS;            // (3072,512)
  unsigned short* WTp   = WTall + 6 * DD;          // (2,512,512)
  unsigned short* hWT   = WTp + 2 * DD;            // (2,2,1024,512)
  float* qkvbias        = (float*)(hWT + 4 * LHW); // 3072 fp32

  // --- prep: 2 dispatches ---
  k_prep_w<<<4096, 256, 0, stream>>>(lW, rW, lhwW, rhwW, WTall, WTp, hWT);
  k_prep_x<<<2092, 256, 0, stream>>>(x, lpad, rpad, lb, rb, nin, qkvbias);

  const int MQ = B_ * S2_;   // 8320

  // --- fused QKV both sides: (8320 x 3072), 128^2 2-phase + XCD swizzle ---
  {
    dim3 g(3072 / 128, MQ / 128, 1);   // (24, 65) -> 1560 blocks, %8==0
    k_gemm_mfma<<<g, 256, 0, stream>>>(nin, WTall, qkvbias, qkv, MQ, 3072, D_);
  }

  // --- attention, both sides, 4 rows/wave ---
  k_attn_window<<<(2 * B_ * S_) / 16, 256, 0, stream>>>(qkv, ctx);

  // --- proj + fused rel-add, z-batched over side (128^2 kernel) ---
  {
    dim3 g(D_ / 128, (B_ * S_) / 128, 2);   // (4, 64, 2)
    k_gemm_proj<<<g, 256, 0, stream>>>(ctx, WTp, nin, lb + 3 * D_, rb + 3 * D_,
                                       lw, rw, hwx);
  }

  // --- highway layers: 256^2 8-phase + fused gate, z-batched over side ---
  {
    dim3 g(1024 / 256, (B_ * S_) / 256, 2);   // (4, 32, 2)
    k_gemm256<1><<<g, 512, 0, stream>>>(hwx, MS, hWT, 2 * LHW,
                                        lhwb, rhwb, hwy, nullptr,
                                        B_ * S_, 1024);
    k_gemm256<2><<<g, 512, 0, stream>>>(hwy, MS, hWT + LHW, 2 * LHW,
                                        lhwb + 1024, rhwb + 1024,
                                        nullptr, out, B_ * S_, 1024);
  }
}

// Round 10
// 234.463 us; speedup vs baseline: 1.0079x; 1.0079x over previous
//
#include <hip/hip_runtime.h>

// SelfAttentiveLBLBiLM on MI355X — round 17.
// r16 post-mortem: gate-LDS on 256^2 hw = neutral/worse (236.3); at 1
// block/CU the tail vmcnt(0)+barrier serializes where scalar loads used to
// overlap. Re-audit: "256^2 helped hw" (r8) was confounded — r7's 128^2 hw
// carried the scalar-xv tax, r8's 256^2 had 2.84M conflicts. Direct data
// (QKV same shape): 2-phase 128^2 = 597 TF vs 256^2-8ph = 528 TF at K=512.
// This round: hw -> 128^2 2-phase (r7 structure) + XCD swizzle + gate-xv
// via 16KB LDS slice (XOR-involution both sides, conflict-free); 1024
// blocks = 4/CU, co-resident blocks hide the drains. prep_w hw mapping
// reverts to r7's 32-block (nl,g) pairing matching 128^2 wave geometry.
// Dispatches: prep_w, prep_x, qkv(128^2+swz), attn(4-row),
// proj+rel(128^2 sliding), hw 128^2 2-phase x2 (gate via LDS).

#define B_ 8
#define S_ 1024
#define D_ 512
#define H_ 8
#define DK_ 64
#define WIDTH_ 8
#define S2_ 1040
#define NHW_ 2

typedef short bf16x8 __attribute__((ext_vector_type(8)));
typedef float f32x4 __attribute__((ext_vector_type(4)));

__device__ __forceinline__ float us2f(unsigned short u) {
  union { unsigned int i; float f; } c; c.i = ((unsigned int)u) << 16; return c.f;
}
__device__ __forceinline__ unsigned short f2us(float f) {
  union { float f; unsigned int i; } c; c.f = f;
  unsigned int x = c.i;
  return (unsigned short)((x + 0x7fffu + ((x >> 16) & 1u)) >> 16);
}
__device__ __forceinline__ unsigned int pack2(float a, float b) {
  return (unsigned int)f2us(a) | ((unsigned int)f2us(b) << 16);
}
__device__ __forceinline__ void async16(const void* g, void* l) {
  __builtin_amdgcn_global_load_lds(
      (const __attribute__((address_space(1))) void*)g,
      (__attribute__((address_space(3))) void*)l, 16, 0, 0);
}
__device__ __forceinline__ void unpack8(uint4 u, float* f) {
  unsigned int w[4] = {u.x, u.y, u.z, u.w};
  #pragma unroll
  for (int c = 0; c < 4; ++c) {
    union { unsigned int i; float g; } lo, hi;
    lo.i = w[c] << 16;
    hi.i = w[c] & 0xffff0000u;
    f[2 * c] = lo.g;
    f[2 * c + 1] = hi.g;
  }
}

// ---------------------------------------------------------------------------
// Prep (weights): [0,2048) attn W transpose; [2048,4096) hw W transpose.
// hw mapping (r7 pairing for 128^2 tiles): orig col c (nl: c<512, g: c>=512)
// -> BT row q = (2*(cm>>4) + isg)*16 + (cm&15); nl at q, g at q+16.
__global__ __launch_bounds__(256) void k_prep_w(
    const float* __restrict__ lW, const float* __restrict__ rW,
    const float* __restrict__ lhwW, const float* __restrict__ rhwW,
    unsigned short* __restrict__ WTall, unsigned short* __restrict__ WTp,
    unsigned short* __restrict__ hWT)
{
  __shared__ float tile[32][33];
  const size_t DD = (size_t)D_ * D_;
  int bx = blockIdx.x;
  int tx = threadIdx.x & 31, ty = threadIdx.x >> 5;

  if (bx < 2048) {                     // ---- attn transpose
    int sl = bx >> 8, rem = bx & 255;
    int side = sl >> 2, slice = sl & 3;
    int c0 = (rem & 15) * 32, r0 = (rem >> 4) * 32;
    const float* src = (side ? rW : lW) + (size_t)slice * DD;
    unsigned short* dst = (slice < 3) ? WTall + (size_t)(side * 3 + slice) * DD
                                      : WTp + (size_t)side * DD;
    #pragma unroll
    for (int i = 0; i < 4; ++i)
      tile[ty + i * 8][tx] = src[(size_t)(r0 + ty + i * 8) * D_ + c0 + tx];
    __syncthreads();
    #pragma unroll
    for (int i = 0; i < 4; ++i)
      dst[(size_t)(c0 + ty + i * 8) * D_ + r0 + tx] = f2us(tile[tx][ty + i * 8]);
    return;
  }
  // ---- hw transpose + interleave (r7 128^2 pairing)
  int idx = bx - 2048;
  int sl = idx >> 9, rem = idx & 511;    // sl: side*2+layer
  int c0 = (rem & 31) * 32, r0 = (rem >> 5) * 32;
  const float* src = ((sl >> 1) ? rhwW : lhwW) + (size_t)(sl & 1) * 512 * 1024;
  unsigned short* dst = hWT + (size_t)sl * 1024 * 512;
  #pragma unroll
  for (int i = 0; i < 4; ++i)
    tile[ty + i * 8][tx] = src[(size_t)(r0 + ty + i * 8) * 1024 + c0 + tx];
  __syncthreads();
  #pragma unroll
  for (int i = 0; i < 4; ++i) {
    int c = c0 + ty + i * 8;
    int q = (2 * ((c & 511) >> 4) + (c >= 512 ? 1 : 0)) * 16 + (c & 15);
    dst[(size_t)q * 512 + r0 + tx] = f2us(tile[tx][ty + i * 8]);
  }
}

// ---------------------------------------------------------------------------
// Prep (activations): build new_in + qkv bias tail.
__global__ __launch_bounds__(256) void k_prep_x(
    const float* __restrict__ x,
    const float* __restrict__ lpad, const float* __restrict__ rpad,
    const float* __restrict__ lb, const float* __restrict__ rb,
    unsigned short* __restrict__ nin, float* __restrict__ qkvbias)
{
  int gid = blockIdx.x * 256 + threadIdx.x;
  const int NTH = B_ * S2_ * 64;       // 532,480
  if (gid >= NTH) {
    int t = gid - NTH;
    if (t < 1536) qkvbias[t] = lb[t];
    else if (t < 3072) qkvbias[t] = rb[t - 1536];
    return;
  }
  int c8 = (gid & 63) << 3;
  int row = gid >> 6;
  int b = row / S2_;
  int t = row - b * S2_;
  const float* src;
  if (t < WIDTH_)            src = lpad + (size_t)t * D_ + c8;
  else if (t >= S_ + WIDTH_) src = rpad + (size_t)(t - S_ - WIDTH_) * D_ + c8;
  else                       src = x + ((size_t)b * S_ + (t - WIDTH_)) * D_ + c8;
  float4 a = *reinterpret_cast<const float4*>(src);
  float4 c = *reinterpret_cast<const float4*>(src + 4);
  uint4 o;
  o.x = pack2(a.x, a.y); o.y = pack2(a.z, a.w);
  o.z = pack2(c.x, c.y); o.w = pack2(c.z, c.w);
  *reinterpret_cast<uint4*>(nin + (size_t)row * D_ + c8) = o;
}

// ---------------------------------------------------------------------------
// MFMA GEMM (QKV): C(M,N) = A(M,K) @ BT(N,K)^T + bias(N).
// BK=64, XOR-swizzled LDS, tile 128x128, 4 waves, XCD-swizzled grid.
__global__ __launch_bounds__(256) void k_gemm_mfma(
    const unsigned short* __restrict__ A,
    const unsigned short* __restrict__ BT,
    const float* __restrict__ bias,
    unsigned short* __restrict__ C,
    int M, int N, int K)
{
  __shared__ unsigned short As[128 * 64];
  __shared__ unsigned short Bs[128 * 64];

  const int tid = threadIdx.x;
  const int w = tid >> 6;
  const int l = tid & 63;

  // bijective XCD swizzle (nwg % 8 == 0)
  const int gx = gridDim.x;
  const int nwg = gx * gridDim.y;
  const int flat = blockIdx.y * gx + blockIdx.x;
  const int cpx = nwg >> 3;
  const int nf = (flat & 7) * cpx + (flat >> 3);
  const int bm = (nf / gx) * 128;
  const int bn = (nf % gx) * 128;

  const int wrow = (w >> 1) * 64;
  const int wcol = (w & 1) * 64;

  const int lr = l >> 3;
  const int sk = (((l & 7) ^ lr) & 7) * 8;
  const unsigned short* Ap = A + (size_t)(bm + w * 8 + lr) * K + sk;
  const unsigned short* Bp = BT + (size_t)(bn + w * 8 + lr) * K + sk;
  unsigned short* lA = &As[w * 512];
  unsigned short* lB = &Bs[w * 512];
  const size_t K32 = (size_t)32 * K;

  const int fl = l & 15;
  const int fq = l >> 4;
  const int fx = fl & 7;

  f32x4 acc[4][4];
  #pragma unroll
  for (int mi = 0; mi < 4; ++mi)
    #pragma unroll
    for (int ni = 0; ni < 4; ++ni) acc[mi][ni] = (f32x4){0.f, 0.f, 0.f, 0.f};

  for (int k0 = 0; k0 < K; k0 += 64) {
    #pragma unroll
    for (int r = 0; r < 4; ++r) {
      async16(Ap + k0 + r * K32, lA + r * 2048);
      async16(Bp + k0 + r * K32, lB + r * 2048);
    }
    __syncthreads();
    #pragma unroll
    for (int s = 0; s < 2; ++s) {
      bf16x8 af[4], bfr[4];
      #pragma unroll
      for (int mi = 0; mi < 4; ++mi)
        af[mi] = *reinterpret_cast<const bf16x8*>(
            &As[(wrow + mi * 16 + fl) * 64 + (((s * 4 + fq) ^ fx) * 8)]);
      #pragma unroll
      for (int ni = 0; ni < 4; ++ni)
        bfr[ni] = *reinterpret_cast<const bf16x8*>(
            &Bs[(wcol + ni * 16 + fl) * 64 + (((s * 4 + fq) ^ fx) * 8)]);
      #pragma unroll
      for (int mi = 0; mi < 4; ++mi)
        #pragma unroll
        for (int ni = 0; ni < 4; ++ni)
          acc[mi][ni] = __builtin_amdgcn_mfma_f32_16x16x32_bf16(
              af[mi], bfr[ni], acc[mi][ni], 0, 0, 0);
    }
    __syncthreads();
  }

  float bv[4];
  #pragma unroll
  for (int ni = 0; ni < 4; ++ni) bv[ni] = bias[bn + wcol + ni * 16 + fl];

  const int rbase = (l >> 4) * 4;
  #pragma unroll
  for (int mi = 0; mi < 4; ++mi) {
    #pragma unroll
    for (int r = 0; r < 4; ++r) {
      int row = bm + wrow + mi * 16 + rbase + r;
      unsigned short* Cp = C + (size_t)row * N + bn + wcol + fl;
      #pragma unroll
      for (int ni = 0; ni < 4; ++ni)
        Cp[ni * 16] = f2us(acc[mi][ni][r] + bv[ni]);
    }
  }
}

// ---------------------------------------------------------------------------
// Highway GEMM 128^2 2-phase + fused gate, gate-xv via 16KB LDS slice.
// BT rows pair (nl,g) via r7 mapping; out col oc = (bn+wcol)/2 + p*16 + fl.
template <bool FINAL>
__global__ __launch_bounds__(256) void k_gemm_hw(
    const unsigned short* __restrict__ Xsrc,
    const unsigned short* __restrict__ BTb, size_t bStrZ,
    const float* __restrict__ bias0, const float* __restrict__ bias1,
    unsigned short* __restrict__ Obf,
    float* __restrict__ Ofp)
{
  __shared__ unsigned short As[128 * 64];
  __shared__ unsigned short Bs[128 * 64];
  const int K = 512;
  const size_t MS = (size_t)B_ * S_ * D_;

  const int z = blockIdx.z;
  const unsigned short* A = Xsrc + (size_t)z * MS;
  const unsigned short* BT = BTb + (size_t)z * bStrZ;
  const float* bias = z ? bias1 : bias0;

  const int tid = threadIdx.x;
  const int w = tid >> 6;
  const int l = tid & 63;

  // XCD swizzle within z-plane (512 blocks, %8==0)
  const int gx = gridDim.x;
  const int nwg = gx * gridDim.y;
  const int flat = blockIdx.y * gx + blockIdx.x;
  const int cpx = nwg >> 3;
  const int nf = (flat & 7) * cpx + (flat >> 3);
  const int bm = (nf / gx) * 128;
  const int bn = (nf % gx) * 128;

  const int wrow = (w >> 1) * 64;
  const int wcol = (w & 1) * 64;

  const int lr = l >> 3;
  const int sk = (((l & 7) ^ lr) & 7) * 8;
  const unsigned short* Ap = A + (size_t)(bm + w * 8 + lr) * K + sk;
  const unsigned short* Bp = BT + (size_t)(bn + w * 8 + lr) * K + sk;
  unsigned short* lA = &As[w * 512];
  unsigned short* lB = &Bs[w * 512];
  const size_t K32 = (size_t)32 * K;

  const int fl = l & 15;
  const int fq = l >> 4;
  const int fx = fl & 7;

  f32x4 acc[4][4];
  #pragma unroll
  for (int mi = 0; mi < 4; ++mi)
    #pragma unroll
    for (int ni = 0; ni < 4; ++ni) acc[mi][ni] = (f32x4){0.f, 0.f, 0.f, 0.f};

  for (int k0 = 0; k0 < K; k0 += 64) {
    #pragma unroll
    for (int r = 0; r < 4; ++r) {
      async16(Ap + k0 + r * K32, lA + r * 2048);
      async16(Bp + k0 + r * K32, lB + r * 2048);
    }
    __syncthreads();
    #pragma unroll
    for (int s = 0; s < 2; ++s) {
      bf16x8 af[4], bfr[4];
      #pragma unroll
      for (int mi = 0; mi < 4; ++mi)
        af[mi] = *reinterpret_cast<const bf16x8*>(
            &As[(wrow + mi * 16 + fl) * 64 + (((s * 4 + fq) ^ fx) * 8)]);
      #pragma unroll
      for (int ni = 0; ni < 4; ++ni)
        bfr[ni] = *reinterpret_cast<const bf16x8*>(
            &Bs[(wcol + ni * 16 + fl) * 64 + (((s * 4 + fq) ^ fx) * 8)]);
      #pragma unroll
      for (int mi = 0; mi < 4; ++mi)
        #pragma unroll
        for (int ni = 0; ni < 4; ++ni)
          acc[mi][ni] = __builtin_amdgcn_mfma_f32_16x16x32_bf16(
              af[mi], bfr[ni], acc[mi][ni], 0, 0, 0);
    }
    __syncthreads();
  }

  // ---- gate-slice stage: A[bm..bm+128) x [bn/2 .. bn/2+64) -> As (16KB).
  // LDS short s of row holds global col short (bn/2) + (s ^ ((row&12)<<2)).
  // dst = wave-uniform base + lane*16B (global_load_lds requirement).
  {
    const unsigned short* gs = A + (size_t)bm * 512 + (bn >> 1);
    #pragma unroll
    for (int i = 0; i < 4; ++i) {
      int row = i * 32 + (tid >> 3);
      int cb = tid & 7;
      int ss = (cb * 8) ^ ((row & 12) << 2);
      async16(gs + (size_t)row * 512 + ss, &As[row * 64 + cb * 8]);
    }
  }
  asm volatile("s_waitcnt vmcnt(0)" ::: "memory");
  __syncthreads();

  // ---- gate epilogue (xv from LDS, 2-way max bank aliasing = free)
  const int ocb = ((bn + wcol) >> 1) + fl;
  float bnl[2], bg[2];
  #pragma unroll
  for (int p = 0; p < 2; ++p) {
    bnl[p] = bias[ocb + p * 16];
    bg[p]  = bias[512 + ocb + p * 16];
  }
  const int rbase = fq * 4;
  const int crel0 = (wcol >> 1) + fl;
  #pragma unroll
  for (int mi = 0; mi < 4; ++mi) {
    #pragma unroll
    for (int r = 0; r < 4; ++r) {
      int lrow = wrow + mi * 16 + rbase + r;
      int row = bm + lrow;
      #pragma unroll
      for (int p = 0; p < 2; ++p) {
        int oc = ocb + p * 16;
        float xv = us2f(As[lrow * 64 + ((crel0 + p * 16) ^ ((lrow & 12) << 2))]);
        float nl = fmaxf(acc[mi][2 * p][r] + bnl[p], 0.f);
        float g  = 1.f / (1.f + __expf(-(acc[mi][2 * p + 1][r] + bg[p])));
        float res = g * xv + (1.f - g) * nl;
        if (FINAL) Ofp[(size_t)row * 1024 + z * 512 + oc] = res;
        else       Obf[(size_t)z * MS + (size_t)row * 512 + oc] = f2us(res);
      }
    }
  }
}

// ---------------------------------------------------------------------------
// Proj GEMM + fused rel-add (128^2 structure, sliding-window rel-add).
__global__ __launch_bounds__(256) void k_gemm_proj(
    const unsigned short* __restrict__ ctx,
    const unsigned short* __restrict__ WTp,    // (2,512,512)
    const unsigned short* __restrict__ nin,    // (B,S2,512)
    const float* __restrict__ lb3, const float* __restrict__ rb3,
    const float* __restrict__ wrel0, const float* __restrict__ wrel1,
    unsigned short* __restrict__ hwx)          // (2,8192,512)
{
  __shared__ unsigned short smem[128 * 136];   // 34.8 KB; staging uses 32 KB
  unsigned short* As = smem;
  unsigned short* Bs = smem + 8192;
  const int K = 512;
  const size_t MS = (size_t)B_ * S_ * D_;

  const int z = blockIdx.z;
  const unsigned short* A = ctx + (size_t)z * MS;
  const unsigned short* BT = WTp + (size_t)z * 512 * 512;
  const float* bias = z ? rb3 : lb3;
  const float* wrel = z ? wrel1 : wrel0;
  const int off = z * WIDTH_;

  const int tid = threadIdx.x;
  const int w = tid >> 6;
  const int l = tid & 63;
  const int bm = blockIdx.y * 128;
  const int bn = blockIdx.x * 128;
  const int wrow = (w >> 1) * 64;
  const int wcol = (w & 1) * 64;

  const int lr = l >> 3;
  const int sk = (((l & 7) ^ lr) & 7) * 8;
  const unsigned short* Ap = A + (size_t)(bm + w * 8 + lr) * K + sk;
  const unsigned short* Bp = BT + (size_t)(bn + w * 8 + lr) * K + sk;
  unsigned short* lA = &As[w * 512];
  unsigned short* lB = &Bs[w * 512];
  const size_t K32 = (size_t)32 * K;

  const int fl = l & 15;
  const int fq = l >> 4;
  const int fx = fl & 7;

  f32x4 acc[4][4];
  #pragma unroll
  for (int mi = 0; mi < 4; ++mi)
    #pragma unroll
    for (int ni = 0; ni < 4; ++ni) acc[mi][ni] = (f32x4){0.f, 0.f, 0.f, 0.f};

  for (int k0 = 0; k0 < K; k0 += 64) {
    #pragma unroll
    for (int r = 0; r < 4; ++r) {
      async16(Ap + k0 + r * K32, lA + r * 2048);
      async16(Bp + k0 + r * K32, lB + r * 2048);
    }
    __syncthreads();
    #pragma unroll
    for (int s = 0; s < 2; ++s) {
      bf16x8 af[4], bfr[4];
      #pragma unroll
      for (int mi = 0; mi < 4; ++mi)
        af[mi] = *reinterpret_cast<const bf16x8*>(
            &As[(wrow + mi * 16 + fl) * 64 + (((s * 4 + fq) ^ fx) * 8)]);
      #pragma unroll
      for (int ni = 0; ni < 4; ++ni)
        bfr[ni] = *reinterpret_cast<const bf16x8*>(
            &Bs[(wcol + ni * 16 + fl) * 64 + (((s * 4 + fq) ^ fx) * 8)]);
      #pragma unroll
      for (int mi = 0; mi < 4; ++mi)
        #pragma unroll
        for (int ni = 0; ni < 4; ++ni)
          acc[mi][ni] = __builtin_amdgcn_mfma_f32_16x16x32_bf16(
              af[mi], bfr[ni], acc[mi][ni], 0, 0, 0);
    }
    __syncthreads();
  }

  // stage bias-added tile into LDS (bf16, ld 136)
  float bv[4];
  #pragma unroll
  for (int ni = 0; ni < 4; ++ni) bv[ni] = bias[bn + wcol + ni * 16 + fl];
  const int rbase = (l >> 4) * 4;
  #pragma unroll
  for (int mi = 0; mi < 4; ++mi)
    #pragma unroll
    for (int r = 0; r < 4; ++r)
      #pragma unroll
      for (int ni = 0; ni < 4; ++ni)
        smem[(wrow + mi * 16 + rbase + r) * 136 + wcol + ni * 16 + fl] =
            f2us(acc[mi][ni][r] + bv[ni]);
  __syncthreads();

  // sliding-window rel-add: thread = (8-consecutive-row group, 8-col chunk).
  const float wj[9] = {wrel[0], wrel[1], wrel[2], wrel[3], wrel[4],
                       wrel[5], wrel[6], wrel[7], wrel[8]};
  const int g8 = (tid >> 4) * 8;
  const int tcol = (tid & 15) * 8;
  {
    int gr0 = bm + g8;
    int b0 = gr0 >> 10, s0 = gr0 & (S_ - 1);
    const unsigned short* np =
        nin + ((size_t)b0 * S2_ + off + s0) * D_ + bn + tcol;
    unsigned short* op = hwx + (size_t)z * MS + (size_t)gr0 * D_ + bn + tcol;
    #pragma unroll
    for (int h = 0; h < 2; ++h) {          // rows h*4 .. h*4+3 of the group
      float a4[4][8];
      #pragma unroll
      for (int i = 0; i < 4; ++i)
        unpack8(*reinterpret_cast<const uint4*>(
            &smem[(g8 + h * 4 + i) * 136 + tcol]), a4[i]);
      #pragma unroll
      for (int t = 0; t < 12; ++t) {       // absolute taps h*4 .. h*4+11
        float nf[8];
        unpack8(*reinterpret_cast<const uint4*>(
            np + (size_t)(h * 4 + t) * D_), nf);
        #pragma unroll
        for (int i = 0; i < 4; ++i) {
          if (t < i || t > i + 8) continue;
          float wv = wj[t - i];
          #pragma unroll
          for (int e = 0; e < 8; ++e) a4[i][e] += wv * nf[e];
        }
      }
      #pragma unroll
      for (int i = 0; i < 4; ++i) {
        uint4 o;
        o.x = pack2(a4[i][0], a4[i][1]); o.y = pack2(a4[i][2], a4[i][3]);
        o.z = pack2(a4[i][4], a4[i][5]); o.w = pack2(a4[i][6], a4[i][7]);
        *reinterpret_cast<uint4*>(op + (size_t)(h * 4 + i) * D_) = o;
      }
    }
  }
}

// ---------------------------------------------------------------------------
// Windowed attention, 4 consecutive rows per wave sharing a 13-row K/V
// window (r11-proven).
__global__ __launch_bounds__(256) void k_attn_window(
    const unsigned short* __restrict__ qkv,
    unsigned short* __restrict__ ctx)
{
  int wid = (blockIdx.x * 256 + threadIdx.x) >> 6;   // dir*2048 + b*256 + sg
  int lane = threadIdx.x & 63;
  int sg = wid & 255;
  int b = (wid >> 8) & 7;
  int dir = wid >> 11;
  int s0 = sg << 2;
  int i0 = s0 + WIDTH_;

  const size_t base = (size_t)b * S2_ * 3072 + dir * 1536;
  const int c0 = lane * 8;

  float qf[4][8];
  #pragma unroll
  for (int r = 0; r < 4; ++r)
    unpack8(*reinterpret_cast<const uint4*>(
        qkv + base + (size_t)(i0 + r) * 3072 + c0), qf[r]);

  float sc[4][10];
  float mx[4] = {-1e30f, -1e30f, -1e30f, -1e30f};
  #pragma unroll
  for (int t = 0; t < 13; ++t) {
    int j = (dir == 0) ? (i0 - 9 + t) : (i0 + t);
    bool ok = (j >= 0 && j < S2_);           // wave-uniform
    float kf[8];
    if (ok)
      unpack8(*reinterpret_cast<const uint4*>(
          qkv + base + (size_t)j * 3072 + 512 + c0), kf);
    #pragma unroll
    for (int r = 0; r < 4; ++r) {
      if (t < r || t > r + 9) continue;      // compile-time prune
      float sv = -1e30f;
      if (ok) {
        float p = qf[r][0] * kf[0];
        #pragma unroll
        for (int e = 1; e < 8; ++e) p += qf[r][e] * kf[e];
        p += __shfl_xor(p, 1);
        p += __shfl_xor(p, 2);
        p += __shfl_xor(p, 4);
        sv = p * 0.125f;
      }
      sc[r][t - r] = sv;
      mx[r] = fmaxf(mx[r], sv);
    }
  }

  float inv[4];
  #pragma unroll
  for (int r = 0; r < 4; ++r) {
    float den = 0.f;
    #pragma unroll
    for (int u = 0; u < 10; ++u) {
      sc[r][u] = (sc[r][u] > -1e29f) ? __expf(sc[r][u] - mx[r]) : 0.f;
      den += sc[r][u];
    }
    inv[r] = 1.f / den;
  }

  float acc[4][8];
  #pragma unroll
  for (int r = 0; r < 4; ++r)
    #pragma unroll
    for (int e = 0; e < 8; ++e) acc[r][e] = 0.f;

  #pragma unroll
  for (int t = 0; t < 13; ++t) {
    int j = (dir == 0) ? (i0 - 9 + t) : (i0 + t);
    bool ok = (j >= 0 && j < S2_);
    float vf[8];
    if (ok)
      unpack8(*reinterpret_cast<const uint4*>(
          qkv + base + (size_t)j * 3072 + 1024 + c0), vf);
    #pragma unroll
    for (int r = 0; r < 4; ++r) {
      if (t < r || t > r + 9) continue;
      if (ok) {
        float p = sc[r][t - r];
        #pragma unroll
        for (int e = 0; e < 8; ++e) acc[r][e] += p * vf[e];
      }
    }
  }

  #pragma unroll
  for (int r = 0; r < 4; ++r) {
    uint4 o;
    o.x = pack2(acc[r][0] * inv[r], acc[r][1] * inv[r]);
    o.y = pack2(acc[r][2] * inv[r], acc[r][3] * inv[r]);
    o.z = pack2(acc[r][4] * inv[r], acc[r][5] * inv[r]);
    o.w = pack2(acc[r][6] * inv[r], acc[r][7] * inv[r]);
    *reinterpret_cast<uint4*>(
        ctx + (((size_t)dir * B_ + b) * S_ + s0 + r) * D_ + c0) = o;
  }
}

// ---------------------------------------------------------------------------
extern "C" void kernel_launch(void* const* d_in, const int* in_sizes, int n_in,
                              void* d_out, int out_size, void* d_ws, size_t ws_size,
                              hipStream_t stream) {
  const float* x    = (const float*)d_in[0];
  const float* lW   = (const float*)d_in[1];
  const float* lb   = (const float*)d_in[2];
  const float* rW   = (const float*)d_in[3];
  const float* rb   = (const float*)d_in[4];
  const float* lpad = (const float*)d_in[5];
  const float* rpad = (const float*)d_in[6];
  const float* lw   = (const float*)d_in[7];
  const float* rw   = (const float*)d_in[8];
  const float* lhwW = (const float*)d_in[9];
  const float* lhwb = (const float*)d_in[10];
  const float* rhwW = (const float*)d_in[11];
  const float* rhwb = (const float*)d_in[12];
  float* out = (float*)d_out;
  unsigned short* ws = (unsigned short*)d_ws;

  const size_t NIN  = (size_t)B_ * S2_ * D_;       // 4,259,840
  const size_t NQKV = (size_t)B_ * S2_ * 3072;     // 25,559,040
  const size_t MS   = (size_t)B_ * S_ * D_;        // 4,194,304
  const size_t DD   = (size_t)D_ * D_;             // 262,144
  const size_t LHW  = (size_t)1024 * 512;          // 524,288

  unsigned short* nin   = ws;
  unsigned short* qkv   = nin + NIN;
  unsigned short* ctx   = qkv + NQKV;              // (2,B,S,D)
  unsigned short* hwx   = ctx + 2 * MS;            // (2,B,S,D)
  unsigned short* hwy   = hwx + 2 * MS;            // (2,B,S,D)
  unsigned short* WTall = hwy + 2 * MS;            // (3072,512)
  unsigned short* WTp   = WTall + 6 * DD;          // (2,512,512)
  unsigned short* hWT   = WTp + 2 * DD;            // (2,2,1024,512)
  float* qkvbias        = (float*)(hWT + 4 * LHW); // 3072 fp32

  // --- prep: 2 dispatches ---
  k_prep_w<<<4096, 256, 0, stream>>>(lW, rW, lhwW, rhwW, WTall, WTp, hWT);
  k_prep_x<<<2092, 256, 0, stream>>>(x, lpad, rpad, lb, rb, nin, qkvbias);

  const int MQ = B_ * S2_;   // 8320

  // --- fused QKV both sides: (8320 x 3072), 128^2 2-phase + XCD swizzle ---
  {
    dim3 g(3072 / 128, MQ / 128, 1);   // (24, 65) -> 1560 blocks, %8==0
    k_gemm_mfma<<<g, 256, 0, stream>>>(nin, WTall, qkvbias, qkv, MQ, 3072, D_);
  }

  // --- attention, both sides, 4 rows/wave ---
  k_attn_window<<<(2 * B_ * S_) / 16, 256, 0, stream>>>(qkv, ctx);

  // --- proj + fused rel-add, z-batched over side (128^2 kernel) ---
  {
    dim3 g(D_ / 128, (B_ * S_) / 128, 2);   // (4, 64, 2)
    k_gemm_proj<<<g, 256, 0, stream>>>(ctx, WTp, nin, lb + 3 * D_, rb + 3 * D_,
                                       lw, rw, hwx);
  }

  // --- highway layers: 128^2 2-phase + fused gate (LDS xv), z-batched ---
  {
    dim3 g(1024 / 128, (B_ * S_) / 128, 2);   // (8, 64, 2) = 1024 blocks
    k_gemm_hw<false><<<g, 256, 0, stream>>>(hwx, hWT, 2 * LHW,
                                            lhwb, rhwb, hwy, nullptr);
    k_gemm_hw<true><<<g, 256, 0, stream>>>(hwy, hWT + LHW, 2 * LHW,
                                           lhwb + 1024, rhwb + 1024,
                                           nullptr, out);
  }
}